// Round 4
// baseline (12439.123 us; speedup 1.0000x reference)
//
#include <hip/hip_runtime.h>
#include <math.h>

// ---------------------------------------------------------------------------
// Generic implicit-GEMM convolution, fp32, 64x64 tile / 4x4 micro.
// Used for layers with small M or N (c1, c7, c8).
// GEMM view: M = Cout, N = BT*OH*OW, K = Cin*KH*KW. M%64==0, N%64==0.
// act: 0 = none, 1 = relu
// ---------------------------------------------------------------------------
template<int KH, int KW>
__global__ __launch_bounds__(256)
void conv_gemm(const float* __restrict__ in, const float* __restrict__ w,
               const float* __restrict__ bias, float* __restrict__ out,
               int Cin, int IH, int IW, int Cout, int OH, int OW,
               int pad, int act)
{
    const int KHW  = KH * KW;
    const int Ktot = Cin * KHW;
    const int OHW  = OH * OW;

    __shared__ float As[16][64];   // [k][m]
    __shared__ float Bs[16][64];   // [k][n]

    const int tid = threadIdx.x;
    const int tx  = tid & 15;      // n micro
    const int ty  = tid >> 4;      // m micro
    const int n0  = blockIdx.x * 64;
    const int m0  = blockIdx.y * 64;

    const int bn   = tid & 63;
    const int bk0  = tid >> 6;      // 0..3
    const int nIdx = n0 + bn;
    const int bt   = nIdx / OHW;
    const int p    = nIdx - bt * OHW;
    const int oy   = p / OW;
    const int ox   = p - oy * OW;
    const float* inb = in + (size_t)bt * Cin * IH * IW;

    const int am = tid >> 2;        // 0..63 (m)
    const int ak = (tid & 3) * 4;   // 0,4,8,12
    const float* wrow = w + (size_t)(m0 + am) * Ktot;

    float acc[4][4] = {{0.f}};

    for (int k0 = 0; k0 < Ktot; k0 += 16) {
        {
            const int kbase = k0 + ak;
            float4 av;
            if (kbase + 4 <= Ktot) av = *(const float4*)(wrow + kbase);
            else { av.x = 0.f; av.y = 0.f; av.z = 0.f; av.w = 0.f; }
            As[ak + 0][am] = av.x;
            As[ak + 1][am] = av.y;
            As[ak + 2][am] = av.z;
            As[ak + 3][am] = av.w;
        }
        #pragma unroll
        for (int q = 0; q < 4; ++q) {
            const int kk = bk0 + q * 4;
            const int k  = k0 + kk;
            float vb = 0.f;
            if (k < Ktot) {
                const int ci = k / KHW;
                const int r  = k - ci * KHW;
                const int ky = r / KW;
                const int kx = r - ky * KW;
                const int iy = oy + ky - pad;
                const int ix = ox + kx - pad;
                if ((unsigned)iy < (unsigned)IH && (unsigned)ix < (unsigned)IW)
                    vb = inb[(ci * IH + iy) * IW + ix];
            }
            Bs[kk][bn] = vb;
        }
        __syncthreads();

        #pragma unroll
        for (int kk = 0; kk < 16; ++kk) {
            const float4 a4 = *(const float4*)&As[kk][ty * 4];
            const float4 b4 = *(const float4*)&Bs[kk][tx * 4];
            const float av[4] = {a4.x, a4.y, a4.z, a4.w};
            const float bv[4] = {b4.x, b4.y, b4.z, b4.w};
            #pragma unroll
            for (int i = 0; i < 4; ++i)
                #pragma unroll
                for (int j = 0; j < 4; ++j)
                    acc[i][j] += av[i] * bv[j];
        }
        __syncthreads();
    }

    #pragma unroll
    for (int i = 0; i < 4; ++i) {
        const int m = m0 + ty * 4 + i;
        const float bv = bias[m];
        #pragma unroll
        for (int j = 0; j < 4; ++j) {
            const int n   = n0 + tx * 4 + j;
            const int bt2 = n / OHW;
            const int p2  = n - bt2 * OHW;
            float vv = acc[i][j] + bv;
            if (act == 1) vv = fmaxf(vv, 0.f);
            out[((size_t)bt2 * Cout + m) * OHW + p2] = vv;
        }
    }
}

// ---------------------------------------------------------------------------
// 128x128 tile / 8x8 micro / BK=16 implicit-GEMM conv, fp32.
// Requires: M%128==0, N%128==0, Ktot%16==0 (holds for c2..c6, pc).
// Split-tile micro layout: thread (tx,ty) owns cols {tx*4..+3, 64+tx*4..+3}
// and rows {ty*4..+3, 64+ty*4..+3} -> b128 LDS reads are 2-way aliased (free).
// ---------------------------------------------------------------------------
template<int KH, int KW>
__global__ __launch_bounds__(256)
void conv_gemm128(const float* __restrict__ in, const float* __restrict__ w,
                  const float* __restrict__ bias, float* __restrict__ out,
                  int Cin, int IH, int IW, int Cout, int OH, int OW,
                  int pad, int act)
{
    const int KHW  = KH * KW;
    const int Ktot = Cin * KHW;
    const int OHW  = OH * OW;

    __shared__ float As[16][128];
    __shared__ float Bs[16][128];

    const int tid = threadIdx.x;
    const int tx  = tid & 15;
    const int ty  = tid >> 4;
    const int n0  = blockIdx.x * 128;
    const int m0  = blockIdx.y * 128;

    const int bn   = tid & 127;
    const int bk   = (tid >> 7) * 8;   // 0 or 8
    const int nIdx = n0 + bn;
    const int bt   = nIdx / OHW;
    const int p    = nIdx - bt * OHW;
    const int oy   = p / OW;
    const int ox   = p - oy * OW;
    const float* inb = in + (size_t)bt * Cin * IH * IW;

    const int am = tid >> 1;           // 0..127 (m)
    const int ak = (tid & 1) * 8;      // 0 or 8
    const float* wrow = w + (size_t)(m0 + am) * Ktot;

    float acc[8][8] = {{0.f}};

    for (int k0 = 0; k0 < Ktot; k0 += 16) {
        {
            const float4 a0 = *(const float4*)(wrow + k0 + ak);
            const float4 a1 = *(const float4*)(wrow + k0 + ak + 4);
            As[ak + 0][am] = a0.x;
            As[ak + 1][am] = a0.y;
            As[ak + 2][am] = a0.z;
            As[ak + 3][am] = a0.w;
            As[ak + 4][am] = a1.x;
            As[ak + 5][am] = a1.y;
            As[ak + 6][am] = a1.z;
            As[ak + 7][am] = a1.w;
        }
        #pragma unroll
        for (int q = 0; q < 8; ++q) {
            const int kk = bk + q;
            const int k  = k0 + kk;
            const int ci = k / KHW;
            const int r  = k - ci * KHW;
            const int ky = r / KW;
            const int kx = r - ky * KW;
            const int iy = oy + ky - pad;
            const int ix = ox + kx - pad;
            float vb = 0.f;
            if ((unsigned)iy < (unsigned)IH && (unsigned)ix < (unsigned)IW)
                vb = inb[(ci * IH + iy) * IW + ix];
            Bs[kk][bn] = vb;
        }
        __syncthreads();

        #pragma unroll
        for (int kk = 0; kk < 16; ++kk) {
            float a[8], b[8];
            *(float4*)&a[0] = *(const float4*)&As[kk][ty * 4];
            *(float4*)&a[4] = *(const float4*)&As[kk][64 + ty * 4];
            *(float4*)&b[0] = *(const float4*)&Bs[kk][tx * 4];
            *(float4*)&b[4] = *(const float4*)&Bs[kk][64 + tx * 4];
            #pragma unroll
            for (int i = 0; i < 8; ++i)
                #pragma unroll
                for (int j = 0; j < 8; ++j)
                    acc[i][j] += a[i] * b[j];
        }
        __syncthreads();
    }

    #pragma unroll
    for (int j = 0; j < 8; ++j) {
        const int n   = n0 + ((j < 4) ? (tx * 4 + j) : (64 + tx * 4 + j - 4));
        const int bt2 = n / OHW;
        const int p2  = n - bt2 * OHW;
        #pragma unroll
        for (int i = 0; i < 8; ++i) {
            const int m = m0 + ((i < 4) ? (ty * 4 + i) : (64 + ty * 4 + i - 4));
            float vv = acc[i][j] + bias[m];
            if (act == 1) vv = fmaxf(vv, 0.f);
            out[((size_t)bt2 * Cout + m) * OHW + p2] = vv;
        }
    }
}

// ---------------------------------------------------------------------------
// Pyramid 1x1 conv with fused channel-concat: B[k] = k<256 ? c3[bt,k,p]
// : broadcast c9[bt,k-256]. M=512, N=768*42, K=320. ReLU epilogue. BK=16.
// ---------------------------------------------------------------------------
__global__ __launch_bounds__(256)
void conv1x1_fp(const float* __restrict__ c3, const float* __restrict__ c9,
                const float* __restrict__ w, const float* __restrict__ bias,
                float* __restrict__ out)
{
    __shared__ float As[16][128];
    __shared__ float Bs[16][128];

    const int tid = threadIdx.x;
    const int tx  = tid & 15;
    const int ty  = tid >> 4;
    const int n0  = blockIdx.x * 128;
    const int m0  = blockIdx.y * 128;

    const int bn   = tid & 127;
    const int bk   = (tid >> 7) * 8;
    const int nIdx = n0 + bn;
    const int bt   = nIdx / 42;
    const int p    = nIdx - bt * 42;

    const int am = tid >> 1;
    const int ak = (tid & 1) * 8;
    const float* wrow = w + (size_t)(m0 + am) * 320;

    float acc[8][8] = {{0.f}};

    for (int k0 = 0; k0 < 320; k0 += 16) {
        {
            const float4 a0 = *(const float4*)(wrow + k0 + ak);
            const float4 a1 = *(const float4*)(wrow + k0 + ak + 4);
            As[ak + 0][am] = a0.x;
            As[ak + 1][am] = a0.y;
            As[ak + 2][am] = a0.z;
            As[ak + 3][am] = a0.w;
            As[ak + 4][am] = a1.x;
            As[ak + 5][am] = a1.y;
            As[ak + 6][am] = a1.z;
            As[ak + 7][am] = a1.w;
        }
        #pragma unroll
        for (int q = 0; q < 8; ++q) {
            const int k = k0 + bk + q;
            float vb;
            if (k < 256) vb = c3[((size_t)bt * 256 + k) * 42 + p];
            else         vb = c9[bt * 64 + (k - 256)];
            Bs[bk + q][bn] = vb;
        }
        __syncthreads();

        #pragma unroll
        for (int kk = 0; kk < 16; ++kk) {
            float a[8], b[8];
            *(float4*)&a[0] = *(const float4*)&As[kk][ty * 4];
            *(float4*)&a[4] = *(const float4*)&As[kk][64 + ty * 4];
            *(float4*)&b[0] = *(const float4*)&Bs[kk][tx * 4];
            *(float4*)&b[4] = *(const float4*)&Bs[kk][64 + tx * 4];
            #pragma unroll
            for (int i = 0; i < 8; ++i)
                #pragma unroll
                for (int j = 0; j < 8; ++j)
                    acc[i][j] += a[i] * b[j];
        }
        __syncthreads();
    }

    #pragma unroll
    for (int j = 0; j < 8; ++j) {
        const int n   = n0 + ((j < 4) ? (tx * 4 + j) : (64 + tx * 4 + j - 4));
        const int bt2 = n / 42;
        const int p2  = n - bt2 * 42;
        #pragma unroll
        for (int i = 0; i < 8; ++i) {
            const int m = m0 + ((i < 4) ? (ty * 4 + i) : (64 + ty * 4 + i - 4));
            const float vv = fmaxf(acc[i][j] + bias[m], 0.f);
            out[((size_t)bt2 * 512 + m) * 42 + p2] = vv;
        }
    }
}

// ---------------------------------------------------------------------------
// Split-K GEMM for the FEAT=21504 projections. in: [N,K], w: [M,K],
// partials out[z, n, m] (no atomics; summed in hseq_k).
// grid: (N/64, M/64, S). kchunk%16==0.
// ---------------------------------------------------------------------------
__global__ __launch_bounds__(256)
void gemm_splitk(const float* __restrict__ in, const float* __restrict__ w,
                 float* __restrict__ out, int K, int M, int kchunk, int strideZ)
{
    __shared__ float As[16][64];
    __shared__ float Bs[16][64];

    const int tid = threadIdx.x;
    const int tx  = tid & 15;
    const int ty  = tid >> 4;
    const int n0  = blockIdx.x * 64;
    const int m0  = blockIdx.y * 64;
    const int kb  = blockIdx.z * kchunk;

    const int ln = tid & 63;
    const int lk = (tid >> 6) * 4;

    const float* inr = in + (size_t)(n0 + ln) * K + kb;
    const float* wr  = w  + (size_t)(m0 + ln) * K + kb;

    float acc[4][4] = {{0.f}};

    for (int k0 = 0; k0 < kchunk; k0 += 16) {
        {
            const float4 av = *(const float4*)(wr + k0 + lk);
            As[lk + 0][ln] = av.x; As[lk + 1][ln] = av.y;
            As[lk + 2][ln] = av.z; As[lk + 3][ln] = av.w;
            const float4 bv = *(const float4*)(inr + k0 + lk);
            Bs[lk + 0][ln] = bv.x; Bs[lk + 1][ln] = bv.y;
            Bs[lk + 2][ln] = bv.z; Bs[lk + 3][ln] = bv.w;
        }
        __syncthreads();
        #pragma unroll
        for (int kk = 0; kk < 16; ++kk) {
            const float4 a4 = *(const float4*)&As[kk][ty * 4];
            const float4 b4 = *(const float4*)&Bs[kk][tx * 4];
            const float av[4] = {a4.x, a4.y, a4.z, a4.w};
            const float bv[4] = {b4.x, b4.y, b4.z, b4.w};
            #pragma unroll
            for (int i = 0; i < 4; ++i)
                #pragma unroll
                for (int j = 0; j < 4; ++j)
                    acc[i][j] += av[i] * bv[j];
        }
        __syncthreads();
    }

    float* ob = out + (size_t)blockIdx.z * strideZ;
    #pragma unroll
    for (int i = 0; i < 4; ++i) {
        const int m = m0 + ty * 4 + i;
        #pragma unroll
        for (int j = 0; j < 4; ++j) {
            const int n = n0 + tx * 4 + j;
            ob[(size_t)n * M + m] = acc[i][j];
        }
    }
}

// ---------------------------------------------------------------------------
// Small helper kernels
// ---------------------------------------------------------------------------
__global__ void stack_x(const float* __restrict__ x1, const float* __restrict__ x2,
                        const float* __restrict__ x3, const float* __restrict__ x4,
                        const float* __restrict__ x5, const float* __restrict__ x6,
                        float* __restrict__ xcat)
{
    const int i = blockIdx.x * 256 + threadIdx.x;   // 768*288
    if (i >= 768 * 288) return;
    const int bt = i / 288;
    const int j  = i - bt * 288;
    const int b  = bt / 6;
    const int t  = bt - b * 6;
    const float* p;
    switch (t) {
        case 0: p = x1; break;
        case 1: p = x2; break;
        case 2: p = x3; break;
        case 3: p = x4; break;
        case 4: p = x5; break;
        default: p = x6; break;
    }
    xcat[i] = p[b * 288 + j];
}

// maxpool (2,2)/(2,2) VALID on [2,3] -> max of flat idx {0,1,3,4}
__global__ void pool_k(const float* __restrict__ c8, float* __restrict__ c9)
{
    const int i = blockIdx.x * 256 + threadIdx.x;   // 768*64
    if (i >= 768 * 64) return;
    const float* p = c8 + (size_t)i * 6;
    c9[i] = fmaxf(fmaxf(p[0], p[1]), fmaxf(p[3], p[4]));
}

// primary capsules: gather + squash over 8
__global__ void caps_u_k(const float* __restrict__ pc, float* __restrict__ u)
{
    const int i = blockIdx.x * 256 + threadIdx.x;   // 768*1344
    if (i >= 768 * 1344) return;
    const int bt = i / 1344;
    const int n  = i - bt * 1344;
    const int p  = n >> 5;    // y*7+x
    const int g  = n & 31;
    const float* base = pc + ((size_t)bt * 256 + g * 8) * 42 + p;
    float s[8];
    float sq = 0.f;
    #pragma unroll
    for (int k = 0; k < 8; ++k) { s[k] = base[k * 42]; sq += s[k] * s[k]; }
    const float scale = (sq / (1.f + sq)) / sqrtf(sq + 1e-9f);
    float* uo = u + (size_t)i * 8;
    #pragma unroll
    for (int k = 0; k < 8; ++k) uo[k] = s[k] * scale;
}

// dynamic routing, 3 iters, one block per bt; u_hat recomputed from capsW.
__global__ __launch_bounds__(256)
void routing_k(const float* __restrict__ u, const float* __restrict__ capsW,
               float* __restrict__ vout)
{
    const int bt   = blockIdx.x;
    const int tid  = threadIdx.x;
    const int lane = tid & 63;
    const int wv   = tid >> 6;

    float un[6][8];
    float blog0[6] = {0.f,0.f,0.f,0.f,0.f,0.f};
    float blog1[6] = {0.f,0.f,0.f,0.f,0.f,0.f};

    #pragma unroll
    for (int q = 0; q < 6; ++q) {
        const int n = tid + q * 256;
        const bool valid = (n < 1344);
        const int ne = valid ? n : 0;
        #pragma unroll
        for (int i = 0; i < 8; ++i)
            un[q][i] = valid ? u[((size_t)bt * 1344 + ne) * 8 + i] : 0.f;
    }

    __shared__ float red[4][32];
    __shared__ float vsh[32];

    for (int it = 0; it < 3; ++it) {
        float s[2][16];
        #pragma unroll
        for (int o = 0; o < 16; ++o) { s[0][o] = 0.f; s[1][o] = 0.f; }

        #pragma unroll
        for (int q = 0; q < 6; ++q) {
            const int n  = tid + q * 256;
            const int ne = (n < 1344) ? n : 0;
            const float b0 = blog0[q], b1 = blog1[q];
            const float m  = fmaxf(b0, b1);
            const float e0 = expf(b0 - m), e1 = expf(b1 - m);
            const float inv = 1.f / (e0 + e1);
            const float cc0 = e0 * inv, cc1 = e1 * inv;
            const float* wr = capsW + (size_t)ne * 256;
            #pragma unroll
            for (int o = 0; o < 16; ++o) {
                float uh0 = 0.f, uh1 = 0.f;
                #pragma unroll
                for (int i = 0; i < 8; ++i) {
                    uh0 += wr[o * 8 + i]       * un[q][i];
                    uh1 += wr[128 + o * 8 + i] * un[q][i];
                }
                s[0][o] += cc0 * uh0;
                s[1][o] += cc1 * uh1;
            }
        }
        #pragma unroll
        for (int c = 0; c < 2; ++c)
            #pragma unroll
            for (int o = 0; o < 16; ++o) {
                float x = s[c][o];
                #pragma unroll
                for (int off = 32; off >= 1; off >>= 1) x += __shfl_xor(x, off, 64);
                s[c][o] = x;
            }
        if (lane == 0) {
            #pragma unroll
            for (int c = 0; c < 2; ++c)
                #pragma unroll
                for (int o = 0; o < 16; ++o) red[wv][c * 16 + o] = s[c][o];
        }
        __syncthreads();
        if (tid < 32) {
            red[0][tid] = red[0][tid] + red[1][tid] + red[2][tid] + red[3][tid];
        }
        __syncthreads();
        if (tid < 32) {
            const int c = tid >> 4;
            float sq = 0.f;
            #pragma unroll
            for (int o = 0; o < 16; ++o) { const float z = red[0][c * 16 + o]; sq += z * z; }
            const float scale = (sq / (1.f + sq)) / sqrtf(sq + 1e-9f);
            vsh[tid] = red[0][tid] * scale;
        }
        __syncthreads();

        if (it == 2) {
            if (tid < 32) vout[bt * 32 + tid] = vsh[tid];
        } else {
            float vr0[16], vr1[16];
            #pragma unroll
            for (int o = 0; o < 16; ++o) { vr0[o] = vsh[o]; vr1[o] = vsh[16 + o]; }
            #pragma unroll
            for (int q = 0; q < 6; ++q) {
                const int n  = tid + q * 256;
                const int ne = (n < 1344) ? n : 0;
                const float* wr = capsW + (size_t)ne * 256;
                float d0 = 0.f, d1 = 0.f;
                #pragma unroll
                for (int o = 0; o < 16; ++o) {
                    float uh0 = 0.f, uh1 = 0.f;
                    #pragma unroll
                    for (int i = 0; i < 8; ++i) {
                        uh0 += wr[o * 8 + i]       * un[q][i];
                        uh1 += wr[128 + o * 8 + i] * un[q][i];
                    }
                    d0 += uh0 * vr0[o];
                    d1 += uh1 * vr1[o];
                }
                blog0[q] += d0;
                blog1[q] += d1;
            }
            __syncthreads();
        }
    }
}

// hseq = sigmoid(sum_z psel + selb) * tanh(sum_z penc + encb)
__global__ void hseq_k(const float* __restrict__ ps, const float* __restrict__ pe,
                       const float* __restrict__ selb, const float* __restrict__ encb,
                       float* __restrict__ h)
{
    const int i = blockIdx.x * 256 + threadIdx.x;   // 768*256
    if (i >= 768 * 256) return;
    const int hh = i & 255;
    float a = 0.f, bsum = 0.f;
    #pragma unroll
    for (int z = 0; z < 8; ++z) {
        a    += ps[(size_t)z * 196608 + i];
        bsum += pe[(size_t)z * 196608 + i];
    }
    const float sg = 1.f / (1.f + expf(-(a + selb[hh])));
    h[i] = sg * tanhf(bsum + encb[hh]);
}

// persistent gated recurrence: one block per batch b, k-state in LDS.
// k_t = sigmoid(k_{t-1} @ wkw.T + h_t @ uw.T + stb); logits = k_6 @ clw.T + clb
__global__ __launch_bounds__(256)
void rnn_k(const float* __restrict__ hseq, const float* __restrict__ wkw,
           const float* __restrict__ uw, const float* __restrict__ stb,
           const float* __restrict__ clw, const float* __restrict__ clb,
           float* __restrict__ out)
{
    const int b = blockIdx.x;
    const int h = threadIdx.x;
    __shared__ float kls[256];
    __shared__ float hls[256];

    const float4* wr4 = (const float4*)(wkw + (size_t)h * 256);
    const float4* ur4 = (const float4*)(uw  + (size_t)h * 256);
    const float sb = stb[h];

    kls[h] = 0.f;
    for (int t = 0; t < 6; ++t) {
        hls[h] = hseq[((size_t)b * 6 + t) * 256 + h];
        __syncthreads();                    // covers kls init (t=0) and hls write
        float s = sb;
        #pragma unroll 4
        for (int j4 = 0; j4 < 64; ++j4) {
            const float4 w4 = wr4[j4];
            const float4 u4 = ur4[j4];
            const float4 k4 = *(const float4*)&kls[j4 * 4];
            const float4 h4 = *(const float4*)&hls[j4 * 4];
            s += w4.x * k4.x + w4.y * k4.y + w4.z * k4.z + w4.w * k4.w
               + u4.x * h4.x + u4.y * h4.y + u4.z * h4.z + u4.w * h4.w;
        }
        const float kn = 1.f / (1.f + expf(-s));
        __syncthreads();                    // all reads of kls done before overwrite
        kls[h] = kn;
    }
    __syncthreads();
    if (h < 2) {
        float s = clb[h];
        const float4* c4p = (const float4*)(clw + (size_t)h * 256);
        for (int j4 = 0; j4 < 64; ++j4) {
            const float4 c4 = c4p[j4];
            const float4 k4 = *(const float4*)&kls[j4 * 4];
            s += c4.x * k4.x + c4.y * k4.y + c4.z * k4.z + c4.w * k4.w;
        }
        out[b * 2 + h] = s;
    }
}

// domain head
__global__ __launch_bounds__(128)
void dom_k(const float* __restrict__ v, const float* __restrict__ d1w,
           const float* __restrict__ d1b, const float* __restrict__ d2w,
           const float* __restrict__ d2b, float* __restrict__ out)
{
    const int b   = blockIdx.x;
    const int tid = threadIdx.x;
    __shared__ float emo[32];
    __shared__ float hid[128];
    if (tid < 32) {
        float s = 0.f;
        for (int t = 0; t < 6; ++t) s += v[(b * 6 + t) * 32 + tid];
        emo[tid] = s * (1.f / 6.f);
    }
    __syncthreads();
    {
        float s = d1b[tid];
        for (int o = 0; o < 32; ++o) s += emo[o] * d1w[tid * 32 + o];
        hid[tid] = fmaxf(s, 0.f);
    }
    __syncthreads();
    if (tid < 2) {
        float s = d2b[tid];
        for (int j = 0; j < 128; ++j) s += hid[j] * d2w[tid * 128 + j];
        out[256 + b * 2 + tid] = s;
    }
}

// ---------------------------------------------------------------------------
extern "C" void kernel_launch(void* const* d_in, const int* in_sizes, int n_in,
                              void* d_out, int out_size, void* d_ws, size_t ws_size,
                              hipStream_t stream)
{
    (void)in_sizes; (void)n_in; (void)out_size; (void)ws_size;

    const float* x1 = (const float*)d_in[0];
    const float* x2 = (const float*)d_in[1];
    const float* x3 = (const float*)d_in[2];
    const float* x4 = (const float*)d_in[3];
    const float* x5 = (const float*)d_in[4];
    const float* x6 = (const float*)d_in[5];
    const float* c1w = (const float*)d_in[6];  const float* c1b = (const float*)d_in[7];
    const float* c2w = (const float*)d_in[8];  const float* c2b = (const float*)d_in[9];
    const float* c3w = (const float*)d_in[10]; const float* c3b = (const float*)d_in[11];
    const float* c4w = (const float*)d_in[12]; const float* c4b = (const float*)d_in[13];
    const float* c5w = (const float*)d_in[14]; const float* c5b = (const float*)d_in[15];
    const float* c6w = (const float*)d_in[16]; const float* c6b = (const float*)d_in[17];
    const float* c7w = (const float*)d_in[18]; const float* c7b = (const float*)d_in[19];
    const float* c8w = (const float*)d_in[20]; const float* c8b = (const float*)d_in[21];
    const float* fpw = (const float*)d_in[22]; const float* fpb = (const float*)d_in[23];
    const float* pcw = (const float*)d_in[24]; const float* pcb = (const float*)d_in[25];
    const float* capsW = (const float*)d_in[26];
    const float* d1w = (const float*)d_in[27]; const float* d1b = (const float*)d_in[28];
    const float* d2w = (const float*)d_in[29]; const float* d2b = (const float*)d_in[30];
    const float* selw = (const float*)d_in[31]; const float* selb = (const float*)d_in[32];
    const float* encw = (const float*)d_in[33]; const float* encb = (const float*)d_in[34];
    const float* wkw = (const float*)d_in[35]; const float* uw = (const float*)d_in[36];
    const float* stb = (const float*)d_in[37];
    const float* clw = (const float*)d_in[38]; const float* clb = (const float*)d_in[39];

    // workspace layout (floats). Aliased: P1: c1->c4->pc ; P2: c2->c5->u ; P4: c6
    float* W = (float*)d_ws;
    size_t off = 0;
    auto A = [&](size_t n) { float* p = W + off; off += n; return p; };
    float* xcat  = A(221184);     // [768,4,8,9]
    float* P1    = A(11796480);   // max(c1 3.54M, c4 11.80M, pc 8.26M)
    float* P2    = A(15728640);   // max(c2 5.50M, c5 15.73M, u 8.26M)
    float* c3buf = A(8257536);    // [768,256,6,7] (pyramid lateral input)
    float* P4    = A(4718592);    // c6 [768,512,3,4]
    float* c7buf = A(1179648);
    float* c8buf = A(294912);
    float* c9buf = A(49152);
    float* pyr   = A(16515072);   // [768,512,6,7] == flat [768,21504]
    float* vbuf  = A(24576);      // [768,2,16]
    float* psel  = A(1572864);    // [8][768,256] split-K partials
    float* penc  = A(1572864);
    float* hseq  = A(196608);     // [768,256]

    const dim3 blk(256);

    stack_x<<<864, blk, 0, stream>>>(x1, x2, x3, x4, x5, x6, xcat);

    // conv chain
    conv_gemm<5,5>   <<<dim3(864, 1),  blk, 0, stream>>>(xcat,  c1w, c1b, P1,    4,   8, 9, 64,   8, 9, 2, 1);
    conv_gemm128<4,4><<<dim3(336, 1),  blk, 0, stream>>>(P1,    c2w, c2b, P2,    64,  8, 9, 128,  7, 8, 1, 1);
    conv_gemm128<4,4><<<dim3(252, 2),  blk, 0, stream>>>(P2,    c3w, c3b, c3buf, 128, 7, 8, 256,  6, 7, 1, 1);
    conv_gemm128<4,4><<<dim3(180, 4),  blk, 0, stream>>>(c3buf, c4w, c4b, P1,    256, 6, 7, 512,  5, 6, 1, 1);
    conv_gemm128<4,4><<<dim3(120, 8),  blk, 0, stream>>>(P1,    c5w, c5b, P2,    512, 5, 6, 1024, 4, 5, 1, 1);
    conv_gemm128<4,4><<<dim3(72, 4),   blk, 0, stream>>>(P2,    c6w, c6b, P4,    1024,4, 5, 512,  3, 4, 1, 1);
    conv_gemm<4,4>   <<<dim3(72, 4),   blk, 0, stream>>>(P4,    c7w, c7b, c7buf, 512, 3, 4, 256,  2, 3, 1, 1);
    conv_gemm<1,1>   <<<dim3(72, 1),   blk, 0, stream>>>(c7buf, c8w, c8b, c8buf, 256, 2, 3, 64,   2, 3, 0, 1);

    pool_k<<<192, blk, 0, stream>>>(c8buf, c9buf);

    // pyramid conv with fused concat, then primary capsules
    conv1x1_fp       <<<dim3(252, 4), blk, 0, stream>>>(c3buf, c9buf, fpw, fpb, pyr);
    conv_gemm128<3,3><<<dim3(252, 2), blk, 0, stream>>>(pyr, pcw, pcb, P1, 512, 6, 7, 256, 6, 7, 1, 0);

    caps_u_k<<<4032, blk, 0, stream>>>(P1, P2);
    routing_k<<<768, blk, 0, stream>>>(P2, capsW, vbuf);

    // sel/enc projections: split-K partials (S=8, kchunk=2688), summed in hseq_k
    gemm_splitk<<<dim3(12, 4, 8), blk, 0, stream>>>(pyr, selw, psel, 21504, 256, 2688, 196608);
    gemm_splitk<<<dim3(12, 4, 8), blk, 0, stream>>>(pyr, encw, penc, 21504, 256, 2688, 196608);
    hseq_k<<<768, blk, 0, stream>>>(psel, penc, selb, encb, hseq);

    // gated recurrence + class logits (persistent, 1 launch)
    rnn_k<<<128, blk, 0, stream>>>(hseq, wkw, uw, stb, clw, clb, (float*)d_out);

    // domain head
    dom_k<<<128, dim3(128), 0, stream>>>(vbuf, d1w, d1b, d2w, d2b, (float*)d_out);
}

// Round 7
// 5116.260 us; speedup vs baseline: 2.4313x; 2.4313x over previous
//
#include <hip/hip_runtime.h>
#include <math.h>

typedef _Float16 f16x8 __attribute__((ext_vector_type(8)));
typedef float    f32x4 __attribute__((ext_vector_type(4)));

// ---------------------------------------------------------------------------
// MFMA implicit-GEMM convolution, fp16 operands / fp32 accumulate.
// GEMM view: M = Cout, N = BT*OH*OW, K = Cin*KH*KW.
// Requires M%128==0, N%128==0, Ktot%64==0.
// Tile 128(M)x128(N), BK=64, 512 threads = 8 waves, wave grid 2(M)x4(N):
// each wave owns 64x32 = 4x2 fragments of 16x16, mfma_f32_16x16x32_f16.
// LDS: A[128][64] f16 + B[128][64] f16 (B stored [n][k]), both with
// byte ^= (row&7)<<4 swizzle -> balanced banks on ds_read/write_b128 (G4).
// MODE 0: natural k order (KHW==16; KHW must divide 64).
// MODE 1: spatial-major k order (3x3): k = (ky*KW+kx)*Cin + ci; requires
//         Cin%64==0 -> per 64-K tile (ky,kx) const, ci contiguous. A and B
//         use the same permutation so the GEMM sum is unchanged.
// act: 0 = none, 1 = relu
// ---------------------------------------------------------------------------
template<int KH, int KW, int MODE>
__global__ __launch_bounds__(512)
void conv_mfma(const float* __restrict__ in, const float* __restrict__ w,
               const float* __restrict__ bias, float* __restrict__ out,
               int Cin, int IH, int IW, int Cout, int OH, int OW,
               int pad, int act)
{
    constexpr int KHW = KH * KW;
    const int Ktot = Cin * KHW;
    const int OHW  = OH * OW;
    const int IHW  = IH * IW;

    __shared__ _Float16 Alds[128 * 64];
    __shared__ _Float16 Blds[128 * 64];

    const int tid  = threadIdx.x;
    const int lane = tid & 63;
    const int wid  = tid >> 6;
    const int wm   = wid >> 2;          // 0..1 -> m offset wm*64
    const int wn   = wid & 3;           // 0..3 -> n offset wn*32
    const int n0   = blockIdx.x * 128;
    const int m0   = blockIdx.y * 128;

    // ---- B staging decode: thread -> one n, 16 k's ----
    const int bn = tid & 127;
    const int kq = tid >> 7;            // 0..3
    const int nIdx = n0 + bn;
    const int bt = nIdx / OHW;
    const int p  = nIdx - bt * OHW;
    const int oy = p / OW;
    const int ox = p - oy * OW;
    const float* inb = in + (size_t)bt * Cin * IHW;

    // ---- A staging decode: thread -> one m row, 16 consecutive k ----
    const int am   = tid >> 2;          // 0..127
    const int ak16 = (tid & 3) * 16;    // k element offset
    const float* wrow = w + (size_t)(m0 + am) * Ktot;

    // ---- MODE 0 precompute: fixed (ky,kx,valid) per element ----
    int off[16];
    unsigned vmask = 0;
    int KADV = 0;
    if (MODE == 0) {
        KADV = (64 / KHW) * IHW;
        #pragma unroll
        for (int i = 0; i < 16; ++i) {
            const int kk = kq * 16 + i;
            const int ci = kk / KHW;
            const int r  = kk - ci * KHW;
            const int ky = r / KW;
            const int kx = r - ky * KW;
            const int iy = oy + ky - pad;
            const int ix = ox + kx - pad;
            if ((unsigned)iy < (unsigned)IH && (unsigned)ix < (unsigned)IW)
                vmask |= (1u << i);
            off[i] = (ci * IH + iy) * IW + ix;
        }
    }

    f32x4 acc[4][2];
    #pragma unroll
    for (int mi = 0; mi < 4; ++mi)
        #pragma unroll
        for (int ni = 0; ni < 2; ++ni)
            acc[mi][ni] = (f32x4){0.f, 0.f, 0.f, 0.f};

    const int nt = Ktot / 64;
    const float* inbt = inb;           // MODE 0: advances by KADV per tile
    const float* wp   = wrow;          // MODE 0: advances by 64 per tile

    for (int t = 0; t < nt; ++t) {
        float va[16];
        float vb[16];

        if (MODE == 0) {
            // A: 16 consecutive fp32 along K
            #pragma unroll
            for (int j4 = 0; j4 < 4; ++j4) {
                const float4 f = *(const float4*)(wp + ak16 + j4 * 4);
                va[j4 * 4 + 0] = f.x; va[j4 * 4 + 1] = f.y;
                va[j4 * 4 + 2] = f.z; va[j4 * 4 + 3] = f.w;
            }
            // B: 16 gathered loads, precomputed offsets
            #pragma unroll
            for (int i = 0; i < 16; ++i)
                vb[i] = (vmask & (1u << i)) ? inbt[off[i]] : 0.f;
        } else {
            // spatial-major: kyx = t>>3 (Cin=512 -> 8 tiles per spatial pos)
            const int kyx    = t >> 3;
            const int ciBase = (t & 7) * 64;
            const int ky = kyx / KW;
            const int kx = kyx - ky * KW;
            const int iy = oy + ky - pad;
            const int ix = ox + kx - pad;
            const bool vt = ((unsigned)iy < (unsigned)IH && (unsigned)ix < (unsigned)IW);
            const int spoff = vt ? (iy * IW + ix) : 0;
            const float* ap = wrow + kyx + (size_t)(ciBase + ak16) * KHW;
            #pragma unroll
            for (int j = 0; j < 16; ++j) va[j] = ap[j * KHW];
            const float* bp = inb + (size_t)(ciBase + kq * 16) * IHW + spoff;
            #pragma unroll
            for (int i = 0; i < 16; ++i) vb[i] = vt ? bp[i * IHW] : 0.f;
        }

        // pack to f16 and write swizzled LDS (2x b128 per operand per thread)
        f16x8 ha0, ha1, hb0, hb1;
        #pragma unroll
        for (int j = 0; j < 8; ++j) {
            ha0[j] = (_Float16)va[j];
            ha1[j] = (_Float16)va[j + 8];
            hb0[j] = (_Float16)vb[j];
            hb1[j] = (_Float16)vb[j + 8];
        }
        {
            const int base = am * 128 + ak16 * 2;   // bytes
            const int sw   = (am & 7) << 4;
            *(f16x8*)((char*)Alds + ((base +  0) ^ sw)) = ha0;
            *(f16x8*)((char*)Alds + ((base + 16) ^ sw)) = ha1;
        }
        {
            const int base = bn * 128 + kq * 32;    // bytes
            const int sw   = (bn & 7) << 4;
            *(f16x8*)((char*)Blds + ((base +  0) ^ sw)) = hb0;
            *(f16x8*)((char*)Blds + ((base + 16) ^ sw)) = hb1;
        }
        __syncthreads();

        // compute: 2 ksteps of 32, fragment reads swizzled
        #pragma unroll
        for (int ks = 0; ks < 2; ++ks) {
            f16x8 af[4], bf[2];
            #pragma unroll
            for (int mi = 0; mi < 4; ++mi) {
                const int row = wm * 64 + mi * 16 + (lane & 15);
                const int byte = (row * 128 + ks * 64 + (lane >> 4) * 16)
                                 ^ ((row & 7) << 4);
                af[mi] = *(const f16x8*)((const char*)Alds + byte);
            }
            #pragma unroll
            for (int ni = 0; ni < 2; ++ni) {
                const int row = wn * 32 + ni * 16 + (lane & 15);
                const int byte = (row * 128 + ks * 64 + (lane >> 4) * 16)
                                 ^ ((row & 7) << 4);
                bf[ni] = *(const f16x8*)((const char*)Blds + byte);
            }
            #pragma unroll
            for (int mi = 0; mi < 4; ++mi)
                #pragma unroll
                for (int ni = 0; ni < 2; ++ni)
                    acc[mi][ni] = __builtin_amdgcn_mfma_f32_16x16x32_f16(
                        af[mi], bf[ni], acc[mi][ni], 0, 0, 0);
        }
        __syncthreads();

        if (MODE == 0) { inbt += KADV; wp += 64; }
    }

    // epilogue: D row (M) = (lane>>4)*4 + reg, col (N) = lane&15  [m89]
    #pragma unroll
    for (int ni = 0; ni < 2; ++ni) {
        const int n   = n0 + wn * 32 + ni * 16 + (lane & 15);
        const int bt2 = n / OHW;
        const int p2  = n - bt2 * OHW;
        #pragma unroll
        for (int mi = 0; mi < 4; ++mi) {
            const int mbase = m0 + wm * 64 + mi * 16 + (lane >> 4) * 4;
            #pragma unroll
            for (int r = 0; r < 4; ++r) {
                const int m = mbase + r;
                float vv = acc[mi][ni][r] + bias[m];
                if (act == 1) vv = fmaxf(vv, 0.f);
                out[((size_t)bt2 * Cout + m) * OHW + p2] = vv;
            }
        }
    }
}

// ---------------------------------------------------------------------------
// fp32 64x64-tile implicit-GEMM conv (c1, c8: M==64 or tiny K).
// ---------------------------------------------------------------------------
template<int KH, int KW>
__global__ __launch_bounds__(256)
void conv_gemm(const float* __restrict__ in, const float* __restrict__ w,
               const float* __restrict__ bias, float* __restrict__ out,
               int Cin, int IH, int IW, int Cout, int OH, int OW,
               int pad, int act)
{
    const int KHW  = KH * KW;
    const int Ktot = Cin * KHW;
    const int OHW  = OH * OW;

    __shared__ float As[16][64];
    __shared__ float Bs[16][64];

    const int tid = threadIdx.x;
    const int tx  = tid & 15;
    const int ty  = tid >> 4;
    const int n0  = blockIdx.x * 64;
    const int m0  = blockIdx.y * 64;

    const int bn   = tid & 63;
    const int bk0  = tid >> 6;
    const int nIdx = n0 + bn;
    const int bt   = nIdx / OHW;
    const int p    = nIdx - bt * OHW;
    const int oy   = p / OW;
    const int ox   = p - oy * OW;
    const float* inb = in + (size_t)bt * Cin * IH * IW;

    const int am = tid >> 2;
    const int ak = (tid & 3) * 4;
    const float* wrow = w + (size_t)(m0 + am) * Ktot;

    float acc[4][4] = {{0.f}};

    for (int k0 = 0; k0 < Ktot; k0 += 16) {
        {
            const int kbase = k0 + ak;
            float4 av;
            if (kbase + 4 <= Ktot) av = *(const float4*)(wrow + kbase);
            else { av.x = 0.f; av.y = 0.f; av.z = 0.f; av.w = 0.f; }
            As[ak + 0][am] = av.x;
            As[ak + 1][am] = av.y;
            As[ak + 2][am] = av.z;
            As[ak + 3][am] = av.w;
        }
        #pragma unroll
        for (int q = 0; q < 4; ++q) {
            const int kk = bk0 + q * 4;
            const int k  = k0 + kk;
            float vb = 0.f;
            if (k < Ktot) {
                const int ci = k / KHW;
                const int r  = k - ci * KHW;
                const int ky = r / KW;
                const int kx = r - ky * KW;
                const int iy = oy + ky - pad;
                const int ix = ox + kx - pad;
                if ((unsigned)iy < (unsigned)IH && (unsigned)ix < (unsigned)IW)
                    vb = inb[(ci * IH + iy) * IW + ix];
            }
            Bs[kk][bn] = vb;
        }
        __syncthreads();

        #pragma unroll
        for (int kk = 0; kk < 16; ++kk) {
            const float4 a4 = *(const float4*)&As[kk][ty * 4];
            const float4 b4 = *(const float4*)&Bs[kk][tx * 4];
            const float av[4] = {a4.x, a4.y, a4.z, a4.w};
            const float bv[4] = {b4.x, b4.y, b4.z, b4.w};
            #pragma unroll
            for (int i = 0; i < 4; ++i)
                #pragma unroll
                for (int j = 0; j < 4; ++j)
                    acc[i][j] += av[i] * bv[j];
        }
        __syncthreads();
    }

    #pragma unroll
    for (int i = 0; i < 4; ++i) {
        const int m = m0 + ty * 4 + i;
        const float bv = bias[m];
        #pragma unroll
        for (int j = 0; j < 4; ++j) {
            const int n   = n0 + tx * 4 + j;
            const int bt2 = n / OHW;
            const int p2  = n - bt2 * OHW;
            float vv = acc[i][j] + bv;
            if (act == 1) vv = fmaxf(vv, 0.f);
            out[((size_t)bt2 * Cout + m) * OHW + p2] = vv;
        }
    }
}

// ---------------------------------------------------------------------------
// Pyramid 1x1 conv with fused channel-concat (fp32, 128-tile, BK=16).
// ---------------------------------------------------------------------------
__global__ __launch_bounds__(256)
void conv1x1_fp(const float* __restrict__ c3, const float* __restrict__ c9,
                const float* __restrict__ w, const float* __restrict__ bias,
                float* __restrict__ out)
{
    __shared__ float As[16][128];
    __shared__ float Bs[16][128];

    const int tid = threadIdx.x;
    const int tx  = tid & 15;
    const int ty  = tid >> 4;
    const int n0  = blockIdx.x * 128;
    const int m0  = blockIdx.y * 128;

    const int bn   = tid & 127;
    const int bk   = (tid >> 7) * 8;
    const int nIdx = n0 + bn;
    const int bt   = nIdx / 42;
    const int p    = nIdx - bt * 42;

    const int am = tid >> 1;
    const int ak = (tid & 1) * 8;
    const float* wrow = w + (size_t)(m0 + am) * 320;

    float acc[8][8] = {{0.f}};

    for (int k0 = 0; k0 < 320; k0 += 16) {
        {
            const float4 a0 = *(const float4*)(wrow + k0 + ak);
            const float4 a1 = *(const float4*)(wrow + k0 + ak + 4);
            As[ak + 0][am] = a0.x; As[ak + 1][am] = a0.y;
            As[ak + 2][am] = a0.z; As[ak + 3][am] = a0.w;
            As[ak + 4][am] = a1.x; As[ak + 5][am] = a1.y;
            As[ak + 6][am] = a1.z; As[ak + 7][am] = a1.w;
        }
        #pragma unroll
        for (int q = 0; q < 8; ++q) {
            const int k = k0 + bk + q;
            float vb;
            if (k < 256) vb = c3[((size_t)bt * 256 + k) * 42 + p];
            else         vb = c9[bt * 64 + (k - 256)];
            Bs[bk + q][bn] = vb;
        }
        __syncthreads();

        #pragma unroll
        for (int kk = 0; kk < 16; ++kk) {
            float a[8], b[8];
            *(float4*)&a[0] = *(const float4*)&As[kk][ty * 4];
            *(float4*)&a[4] = *(const float4*)&As[kk][64 + ty * 4];
            *(float4*)&b[0] = *(const float4*)&Bs[kk][tx * 4];
            *(float4*)&b[4] = *(const float4*)&Bs[kk][64 + tx * 4];
            #pragma unroll
            for (int i = 0; i < 8; ++i)
                #pragma unroll
                for (int j = 0; j < 8; ++j)
                    acc[i][j] += a[i] * b[j];
        }
        __syncthreads();
    }

    #pragma unroll
    for (int j = 0; j < 8; ++j) {
        const int n   = n0 + ((j < 4) ? (tx * 4 + j) : (64 + tx * 4 + j - 4));
        const int bt2 = n / 42;
        const int p2  = n - bt2 * 42;
        #pragma unroll
        for (int i = 0; i < 8; ++i) {
            const int m = m0 + ((i < 4) ? (ty * 4 + i) : (64 + ty * 4 + i - 4));
            const float vv = fmaxf(acc[i][j] + bias[m], 0.f);
            out[((size_t)bt2 * 512 + m) * 42 + p2] = vv;
        }
    }
}

// ---------------------------------------------------------------------------
// Split-K GEMM for FEAT=21504 projections (partials, summed in hseq_k).
// ---------------------------------------------------------------------------
__global__ __launch_bounds__(256)
void gemm_splitk(const float* __restrict__ in, const float* __restrict__ w,
                 float* __restrict__ out, int K, int M, int kchunk, int strideZ)
{
    __shared__ float As[16][64];
    __shared__ float Bs[16][64];

    const int tid = threadIdx.x;
    const int tx  = tid & 15;
    const int ty  = tid >> 4;
    const int n0  = blockIdx.x * 64;
    const int m0  = blockIdx.y * 64;
    const int kb  = blockIdx.z * kchunk;

    const int ln = tid & 63;
    const int lk = (tid >> 6) * 4;

    const float* inr = in + (size_t)(n0 + ln) * K + kb;
    const float* wr  = w  + (size_t)(m0 + ln) * K + kb;

    float acc[4][4] = {{0.f}};

    for (int k0 = 0; k0 < kchunk; k0 += 16) {
        {
            const float4 av = *(const float4*)(wr + k0 + lk);
            As[lk + 0][ln] = av.x; As[lk + 1][ln] = av.y;
            As[lk + 2][ln] = av.z; As[lk + 3][ln] = av.w;
            const float4 bv = *(const float4*)(inr + k0 + lk);
            Bs[lk + 0][ln] = bv.x; Bs[lk + 1][ln] = bv.y;
            Bs[lk + 2][ln] = bv.z; Bs[lk + 3][ln] = bv.w;
        }
        __syncthreads();
        #pragma unroll
        for (int kk = 0; kk < 16; ++kk) {
            const float4 a4 = *(const float4*)&As[kk][ty * 4];
            const float4 b4 = *(const float4*)&Bs[kk][tx * 4];
            const float av[4] = {a4.x, a4.y, a4.z, a4.w};
            const float bv[4] = {b4.x, b4.y, b4.z, b4.w};
            #pragma unroll
            for (int i = 0; i < 4; ++i)
                #pragma unroll
                for (int j = 0; j < 4; ++j)
                    acc[i][j] += av[i] * bv[j];
        }
        __syncthreads();
    }

    float* ob = out + (size_t)blockIdx.z * strideZ;
    #pragma unroll
    for (int i = 0; i < 4; ++i) {
        const int m = m0 + ty * 4 + i;
        #pragma unroll
        for (int j = 0; j < 4; ++j) {
            const int n = n0 + tx * 4 + j;
            ob[(size_t)n * M + m] = acc[i][j];
        }
    }
}

// ---------------------------------------------------------------------------
// Small helper kernels
// ---------------------------------------------------------------------------
__global__ void stack_x(const float* __restrict__ x1, const float* __restrict__ x2,
                        const float* __restrict__ x3, const float* __restrict__ x4,
                        const float* __restrict__ x5, const float* __restrict__ x6,
                        float* __restrict__ xcat)
{
    const int i = blockIdx.x * 256 + threadIdx.x;
    if (i >= 768 * 288) return;
    const int bt = i / 288;
    const int j  = i - bt * 288;
    const int b  = bt / 6;
    const int t  = bt - b * 6;
    const float* p;
    switch (t) {
        case 0: p = x1; break;
        case 1: p = x2; break;
        case 2: p = x3; break;
        case 3: p = x4; break;
        case 4: p = x5; break;
        default: p = x6; break;
    }
    xcat[i] = p[b * 288 + j];
}

__global__ void pool_k(const float* __restrict__ c8, float* __restrict__ c9)
{
    const int i = blockIdx.x * 256 + threadIdx.x;
    if (i >= 768 * 64) return;
    const float* p = c8 + (size_t)i * 6;
    c9[i] = fmaxf(fmaxf(p[0], p[1]), fmaxf(p[3], p[4]));
}

__global__ void caps_u_k(const float* __restrict__ pc, float* __restrict__ u)
{
    const int i = blockIdx.x * 256 + threadIdx.x;
    if (i >= 768 * 1344) return;
    const int bt = i / 1344;
    const int n  = i - bt * 1344;
    const int p  = n >> 5;
    const int g  = n & 31;
    const float* base = pc + ((size_t)bt * 256 + g * 8) * 42 + p;
    float s[8];
    float sq = 0.f;
    #pragma unroll
    for (int k = 0; k < 8; ++k) { s[k] = base[k * 42]; sq += s[k] * s[k]; }
    const float scale = (sq / (1.f + sq)) / sqrtf(sq + 1e-9f);
    float* uo = u + (size_t)i * 8;
    #pragma unroll
    for (int k = 0; k < 8; ++k) uo[k] = s[k] * scale;
}

__global__ __launch_bounds__(256)
void routing_k(const float* __restrict__ u, const float* __restrict__ capsW,
               float* __restrict__ vout)
{
    const int bt   = blockIdx.x;
    const int tid  = threadIdx.x;
    const int lane = tid & 63;
    const int wv   = tid >> 6;

    float un[6][8];
    float blog0[6] = {0.f,0.f,0.f,0.f,0.f,0.f};
    float blog1[6] = {0.f,0.f,0.f,0.f,0.f,0.f};

    #pragma unroll
    for (int q = 0; q < 6; ++q) {
        const int n = tid + q * 256;
        const bool valid = (n < 1344);
        const int ne = valid ? n : 0;
        #pragma unroll
        for (int i = 0; i < 8; ++i)
            un[q][i] = valid ? u[((size_t)bt * 1344 + ne) * 8 + i] : 0.f;
    }

    __shared__ float red[4][32];
    __shared__ float vsh[32];

    for (int it = 0; it < 3; ++it) {
        float s[2][16];
        #pragma unroll
        for (int o = 0; o < 16; ++o) { s[0][o] = 0.f; s[1][o] = 0.f; }

        #pragma unroll
        for (int q = 0; q < 6; ++q) {
            const int n  = tid + q * 256;
            const int ne = (n < 1344) ? n : 0;
            const float b0 = blog0[q], b1 = blog1[q];
            const float m  = fmaxf(b0, b1);
            const float e0 = expf(b0 - m), e1 = expf(b1 - m);
            const float inv = 1.f / (e0 + e1);
            const float cc0 = e0 * inv, cc1 = e1 * inv;
            const float* wr = capsW + (size_t)ne * 256;
            #pragma unroll
            for (int o = 0; o < 16; ++o) {
                float uh0 = 0.f, uh1 = 0.f;
                #pragma unroll
                for (int i = 0; i < 8; ++i) {
                    uh0 += wr[o * 8 + i]       * un[q][i];
                    uh1 += wr[128 + o * 8 + i] * un[q][i];
                }
                s[0][o] += cc0 * uh0;
                s[1][o] += cc1 * uh1;
            }
        }
        #pragma unroll
        for (int c = 0; c < 2; ++c)
            #pragma unroll
            for (int o = 0; o < 16; ++o) {
                float x = s[c][o];
                #pragma unroll
                for (int off = 32; off >= 1; off >>= 1) x += __shfl_xor(x, off, 64);
                s[c][o] = x;
            }
        if (lane == 0) {
            #pragma unroll
            for (int c = 0; c < 2; ++c)
                #pragma unroll
                for (int o = 0; o < 16; ++o) red[wv][c * 16 + o] = s[c][o];
        }
        __syncthreads();
        if (tid < 32) {
            red[0][tid] = red[0][tid] + red[1][tid] + red[2][tid] + red[3][tid];
        }
        __syncthreads();
        if (tid < 32) {
            const int c = tid >> 4;
            float sq = 0.f;
            #pragma unroll
            for (int o = 0; o < 16; ++o) { const float z = red[0][c * 16 + o]; sq += z * z; }
            const float scale = (sq / (1.f + sq)) / sqrtf(sq + 1e-9f);
            vsh[tid] = red[0][tid] * scale;
        }
        __syncthreads();

        if (it == 2) {
            if (tid < 32) vout[bt * 32 + tid] = vsh[tid];
        } else {
            float vr0[16], vr1[16];
            #pragma unroll
            for (int o = 0; o < 16; ++o) { vr0[o] = vsh[o]; vr1[o] = vsh[16 + o]; }
            #pragma unroll
            for (int q = 0; q < 6; ++q) {
                const int n  = tid + q * 256;
                const int ne = (n < 1344) ? n : 0;
                const float* wr = capsW + (size_t)ne * 256;
                float d0 = 0.f, d1 = 0.f;
                #pragma unroll
                for (int o = 0; o < 16; ++o) {
                    float uh0 = 0.f, uh1 = 0.f;
                    #pragma unroll
                    for (int i = 0; i < 8; ++i) {
                        uh0 += wr[o * 8 + i]       * un[q][i];
                        uh1 += wr[128 + o * 8 + i] * un[q][i];
                    }
                    d0 += uh0 * vr0[o];
                    d1 += uh1 * vr1[o];
                }
                blog0[q] += d0;
                blog1[q] += d1;
            }
            __syncthreads();
        }
    }
}

__global__ void hseq_k(const float* __restrict__ ps, const float* __restrict__ pe,
                       const float* __restrict__ selb, const float* __restrict__ encb,
                       float* __restrict__ h)
{
    const int i = blockIdx.x * 256 + threadIdx.x;
    if (i >= 768 * 256) return;
    const int hh = i & 255;
    float a = 0.f, bsum = 0.f;
    #pragma unroll
    for (int z = 0; z < 8; ++z) {
        a    += ps[(size_t)z * 196608 + i];
        bsum += pe[(size_t)z * 196608 + i];
    }
    const float sg = 1.f / (1.f + expf(-(a + selb[hh])));
    h[i] = sg * tanhf(bsum + encb[hh]);
}

__global__ __launch_bounds__(256)
void rnn_k(const float* __restrict__ hseq, const float* __restrict__ wkw,
           const float* __restrict__ uw, const float* __restrict__ stb,
           const float* __restrict__ clw, const float* __restrict__ clb,
           float* __restrict__ out)
{
    const int b = blockIdx.x;
    const int h = threadIdx.x;
    __shared__ float kls[256];
    __shared__ float hls[256];

    const float4* wr4 = (const float4*)(wkw + (size_t)h * 256);
    const float4* ur4 = (const float4*)(uw  + (size_t)h * 256);
    const float sb = stb[h];

    kls[h] = 0.f;
    for (int t = 0; t < 6; ++t) {
        hls[h] = hseq[((size_t)b * 6 + t) * 256 + h];
        __syncthreads();
        float s = sb;
        #pragma unroll 4
        for (int j4 = 0; j4 < 64; ++j4) {
            const float4 w4 = wr4[j4];
            const float4 u4 = ur4[j4];
            const float4 k4 = *(const float4*)&kls[j4 * 4];
            const float4 h4 = *(const float4*)&hls[j4 * 4];
            s += w4.x * k4.x + w4.y * k4.y + w4.z * k4.z + w4.w * k4.w
               + u4.x * h4.x + u4.y * h4.y + u4.z * h4.z + u4.w * h4.w;
        }
        const float kn = 1.f / (1.f + expf(-s));
        __syncthreads();
        kls[h] = kn;
    }
    __syncthreads();
    if (h < 2) {
        float s = clb[h];
        const float4* c4p = (const float4*)(clw + (size_t)h * 256);
        for (int j4 = 0; j4 < 64; ++j4) {
            const float4 c4 = c4p[j4];
            const float4 k4 = *(const float4*)&kls[j4 * 4];
            s += c4.x * k4.x + c4.y * k4.y + c4.z * k4.z + c4.w * k4.w;
        }
        out[b * 2 + h] = s;
    }
}

__global__ __launch_bounds__(128)
void dom_k(const float* __restrict__ v, const float* __restrict__ d1w,
           const float* __restrict__ d1b, const float* __restrict__ d2w,
           const float* __restrict__ d2b, float* __restrict__ out)
{
    const int b   = blockIdx.x;
    const int tid = threadIdx.x;
    __shared__ float emo[32];
    __shared__ float hid[128];
    if (tid < 32) {
        float s = 0.f;
        for (int t = 0; t < 6; ++t) s += v[(b * 6 + t) * 32 + tid];
        emo[tid] = s * (1.f / 6.f);
    }
    __syncthreads();
    {
        float s = d1b[tid];
        for (int o = 0; o < 32; ++o) s += emo[o] * d1w[tid * 32 + o];
        hid[tid] = fmaxf(s, 0.f);
    }
    __syncthreads();
    if (tid < 2) {
        float s = d2b[tid];
        for (int j = 0; j < 128; ++j) s += hid[j] * d2w[tid * 128 + j];
        out[256 + b * 2 + tid] = s;
    }
}

// ---------------------------------------------------------------------------
extern "C" void kernel_launch(void* const* d_in, const int* in_sizes, int n_in,
                              void* d_out, int out_size, void* d_ws, size_t ws_size,
                              hipStream_t stream)
{
    (void)in_sizes; (void)n_in; (void)out_size; (void)ws_size;

    const float* x1 = (const float*)d_in[0];
    const float* x2 = (const float*)d_in[1];
    const float* x3 = (const float*)d_in[2];
    const float* x4 = (const float*)d_in[3];
    const float* x5 = (const float*)d_in[4];
    const float* x6 = (const float*)d_in[5];
    const float* c1w = (const float*)d_in[6];  const float* c1b = (const float*)d_in[7];
    const float* c2w = (const float*)d_in[8];  const float* c2b = (const float*)d_in[9];
    const float* c3w = (const float*)d_in[10]; const float* c3b = (const float*)d_in[11];
    const float* c4w = (const float*)d_in[12]; const float* c4b = (const float*)d_in[13];
    const float* c5w = (const float*)d_in[14]; const float* c5b = (const float*)d_in[15];
    const float* c6w = (const float*)d_in[16]; const float* c6b = (const float*)d_in[17];
    const float* c7w = (const float*)d_in[18]; const float* c7b = (const float*)d_in[19];
    const float* c8w = (const float*)d_in[20]; const float* c8b = (const float*)d_in[21];
    const float* fpw = (const float*)d_in[22]; const float* fpb = (const float*)d_in[23];
    const float* pcw = (const float*)d_in[24]; const float* pcb = (const float*)d_in[25];
    const float* capsW = (const float*)d_in[26];
    const float* d1w = (const float*)d_in[27]; const float* d1b = (const float*)d_in[28];
    const float* d2w = (const float*)d_in[29]; const float* d2b = (const float*)d_in[30];
    const float* selw = (const float*)d_in[31]; const float* selb = (const float*)d_in[32];
    const float* encw = (const float*)d_in[33]; const float* encb = (const float*)d_in[34];
    const float* wkw = (const float*)d_in[35]; const float* uw = (const float*)d_in[36];
    const float* stb = (const float*)d_in[37];
    const float* clw = (const float*)d_in[38]; const float* clb = (const float*)d_in[39];

    // workspace layout (floats). Aliased: P1: c1->c4->pc ; P2: c2->c5->u ; P4: c6
    float* W = (float*)d_ws;
    size_t off = 0;
    auto A = [&](size_t n) { float* p = W + off; off += n; return p; };
    float* xcat  = A(221184);
    float* P1    = A(11796480);
    float* P2    = A(15728640);
    float* c3buf = A(8257536);
    float* P4    = A(4718592);
    float* c7buf = A(1179648);
    float* c8buf = A(294912);
    float* c9buf = A(49152);
    float* pyr   = A(16515072);
    float* vbuf  = A(24576);
    float* psel  = A(1572864);
    float* penc  = A(1572864);
    float* hseq  = A(196608);

    const dim3 blk(256);
    const dim3 blkM(512);

    stack_x<<<864, blk, 0, stream>>>(x1, x2, x3, x4, x5, x6, xcat);

    // conv chain: c1 fp32; c2..c7 fp16 MFMA
    conv_gemm<5,5>    <<<dim3(864, 1), blk,  0, stream>>>(xcat,  c1w, c1b, P1,    4,   8, 9, 64,   8, 9, 2, 1);
    conv_mfma<4,4,0>  <<<dim3(336, 1), blkM, 0, stream>>>(P1,    c2w, c2b, P2,    64,  8, 9, 128,  7, 8, 1, 1);
    conv_mfma<4,4,0>  <<<dim3(252, 2), blkM, 0, stream>>>(P2,    c3w, c3b, c3buf, 128, 7, 8, 256,  6, 7, 1, 1);
    conv_mfma<4,4,0>  <<<dim3(180, 4), blkM, 0, stream>>>(c3buf, c4w, c4b, P1,    256, 6, 7, 512,  5, 6, 1, 1);
    conv_mfma<4,4,0>  <<<dim3(120, 8), blkM, 0, stream>>>(P1,    c5w, c5b, P2,    512, 5, 6, 1024, 4, 5, 1, 1);
    conv_mfma<4,4,0>  <<<dim3(72, 4),  blkM, 0, stream>>>(P2,    c6w, c6b, P4,    1024,4, 5, 512,  3, 4, 1, 1);
    conv_mfma<4,4,0>  <<<dim3(36, 2),  blkM, 0, stream>>>(P4,    c7w, c7b, c7buf, 512, 3, 4, 256,  2, 3, 1, 1);
    conv_gemm<1,1>    <<<dim3(72, 1),  blk,  0, stream>>>(c7buf, c8w, c8b, c8buf, 256, 2, 3, 64,   2, 3, 0, 1);

    pool_k<<<192, blk, 0, stream>>>(c8buf, c9buf);

    // pyramid conv (fp32, fused concat), then primary capsules (fp16 MFMA, spatial-major)
    conv1x1_fp        <<<dim3(252, 4), blk,  0, stream>>>(c3buf, c9buf, fpw, fpb, pyr);
    conv_mfma<3,3,1>  <<<dim3(252, 2), blkM, 0, stream>>>(pyr, pcw, pcb, P1, 512, 6, 7, 256, 6, 7, 1, 0);

    caps_u_k<<<4032, blk, 0, stream>>>(P1, P2);
    routing_k<<<768, blk, 0, stream>>>(P2, capsW, vbuf);

    // sel/enc projections: split-K partials (S=8, kchunk=2688), summed in hseq_k
    gemm_splitk<<<dim3(12, 4, 8), blk, 0, stream>>>(pyr, selw, psel, 21504, 256, 2688, 196608);
    gemm_splitk<<<dim3(12, 4, 8), blk, 0, stream>>>(pyr, encw, penc, 21504, 256, 2688, 196608);
    hseq_k<<<768, blk, 0, stream>>>(psel, penc, selb, encb, hseq);

    // gated recurrence + class logits (persistent, 1 launch)
    rnn_k<<<128, blk, 0, stream>>>(hseq, wkw, uw, stb, clw, clb, (float*)d_out);

    // domain head
    dom_k<<<128, dim3(128), 0, stream>>>(vbuf, d1w, d1b, d2w, d2b, (float*)d_out);
}